// Round 2
// baseline (1465.533 us; speedup 1.0000x reference)
//
#include <hip/hip_runtime.h>
#include <hip/hip_bf16.h>

#define GN 16384
#define GD 128
#define KSPLIT 4
#define KBLK (GN / KSPLIT)        // 4096 k per block
#define PHK 128                   // k per LDS phase
#define NPH (KBLK / PHK)          // 32 phases
#define NSTEP (PHK / 32)          // 4 mfma k-steps per phase
#define BUF_SHORTS (GD * PHK)     // 16384 shorts = 32 KB per buffer
#define OUT_ELEMS (GN * GD)
#define GNW (GN / 32)             // 512 bitmask dwords per adj row

typedef __attribute__((ext_vector_type(8))) short short8;
typedef __attribute__((ext_vector_type(4))) float floatx4;
typedef __attribute__((ext_vector_type(4))) int intx4;
typedef __attribute__((ext_vector_type(4))) unsigned uintx4;

static __device__ __forceinline__ unsigned short f32_to_bf16(float f) {
  unsigned u = __builtin_bit_cast(unsigned, f);
  unsigned r = u + 0x7FFFu + ((u >> 16) & 1u);  // RNE (inputs finite/normal)
  return (unsigned short)(r >> 16);
}

// Kernel 1: xT[d][j] <- bf16(x[j][d])  (4 MiB, L2/L3-resident)
__global__ __launch_bounds__(256) void prep_kernel(const float* __restrict__ x,
                                                   unsigned short* __restrict__ xT) {
  __shared__ unsigned short t[GD][66];
  const int tid = threadIdx.x;
  const int j0 = blockIdx.x * 64;
  for (int i = tid; i < 64 * GD; i += 256) {
    int j = i >> 7, d = i & (GD - 1);
    t[d][j] = f32_to_bf16(x[(size_t)(j0 + j) * GD + d]);
  }
  __syncthreads();
  for (int i = tid; i < GD * 32; i += 256) {
    int d = i >> 5, jp = i & 31;
    unsigned lo = t[d][2 * jp], hi = t[d][2 * jp + 1];
    *reinterpret_cast<unsigned*>(xT + (size_t)d * GN + j0 + 2 * jp) = lo | (hi << 16);
  }
}

// Kernel 1b (REWORKED): bit-pack adj (1 GiB of int32 {0,1}) -> ubits (32 MiB).
// R1's version read 16B-per-128B strided per lane -> L1/L2 sector thrash, est
// ~2.5-3 TB/s. Now: COALESCED global_load_lds staging (1 KB contiguous per
// instr; source pre-swizzled so the LDS row-read is spread across banks), then
// each lane packs its own 32 ints from LDS. Pure streaming: target ~6 TB/s.
// bit i of ubits[w] == adj[w*32 + i] & 1  (same convention as R1).
__global__ __launch_bounds__(256) void pack_kernel(const int* __restrict__ adj,
                                                   unsigned* __restrict__ ubits) {
  __shared__ int sb[4][2048];  // 8 KB per wave
  const int tid = threadIdx.x;
  const int wave = tid >> 6;
  const int lane = tid & 63;
  const int NITER = (GN * GNW) / 64;  // 131072 wave-iters, 64 out-dwords each

  int* const sw = &sb[wave][0];
  int witer = blockIdx.x * 4 + wave;
  const int wstride = gridDim.x * 4;
  for (; witer < NITER; witer += wstride) {
    const int* base = adj + (size_t)witer * 2048;
    // stage 8 KB: slot idx (16B granule) = j*64+lane; owner row l=idx>>3,
    // phys granule g=idx&7 holds GLOBAL granule l*8 + (g ^ (l&7)).
#pragma unroll
    for (int j = 0; j < 8; ++j) {
      int idx = j * 64 + lane;
      int l = idx >> 3, g = idx & 7;
      int G = l * 8 + (g ^ (l & 7));
      __builtin_amdgcn_global_load_lds(
          (const __attribute__((address_space(1))) unsigned int*)(base + G * 4),
          (__attribute__((address_space(3))) unsigned int*)(sw + idx * 4), 16, 0, 0);
    }
    asm volatile("s_waitcnt vmcnt(0)" ::: "memory");
    // lane packs its row: global granule lane*8 + j lives at phys g = j^(lane&7)
    unsigned out = 0;
#pragma unroll
    for (int j = 0; j < 8; ++j) {
      intx4 r = *(const intx4*)(sw + lane * 32 + ((j ^ (lane & 7)) * 4));
      unsigned nib = (unsigned)((r.x & 1) | ((r.y & 1) << 1) | ((r.z & 1) << 2) |
                                ((r.w & 1) << 3));
      out |= nib << (4 * j);
    }
    ubits[(size_t)witer * 64 + lane] = out;
    asm volatile("" ::: "memory");  // keep next iter's staging after these reads
  }
}

// Kernel 2 (RETILED): wave tile 16x128 -> 64x32 (4 M-tiles x 2 col-tiles).
// Motivation: old tiling had every wave ds_read the ENTIRE 32 KB B-tile per
// phase (8x redundancy, ~16k conflicted ds_read_b128/CU = the dominant on-chip
// cost). Now ds_reads/wave/phase = 8 (was 32) and each A-frag expansion feeds
// 2 MFMAs. Bitmask A (4 x uintx4/phase, single-buffered, L2-resident) is what
// makes 4 M-tiles register-affordable. All numerics/k-order identical to R1.
__global__ __launch_bounds__(512, 4) void gemm_kernel(const unsigned* __restrict__ ubits,
                                                      const unsigned short* __restrict__ xT,
                                                      float* __restrict__ partials) {
  __shared__ unsigned short bbuf[2][BUF_SHORTS];  // 2 x 32 KB
  const int tid = threadIdx.x;
  const int wave = tid >> 6;
  const int wr = wave >> 2;  // 0..1: row half (64 rows)
  const int wc = wave & 3;   // 0..3: col quarter (32 cols)
  const int lane = tid & 63;
  const int q = lane >> 4;   // 0..3
  const int m = lane & 15;   // 0..15
  const int ks = blockIdx.y;
  const int kbase = ks * KBLK;

  // staging: 4 granules (16 B) per thread; slot s = tid + 512p; row n = s>>4
  const unsigned short* gptr[4];
  unsigned short* lptr[4];
#pragma unroll
  for (int p = 0; p < 4; ++p) {
    int s = tid + 512 * p;            // 0..2047
    int n = s >> 4;                   // B row (= d) 0..127
    int gsrc = (s & 15) ^ (n & 7);    // XOR swizzle (involution on low 3 bits)
    gptr[p] = xT + (size_t)n * GN + kbase + gsrc * 8;
    lptr[p] = &bbuf[0][0] + (size_t)s * 8;
  }

#define STAGE(bufsel, koff)                                                             \
  do {                                                                                  \
    _Pragma("unroll") for (int p = 0; p < 4; ++p) {                                     \
      __builtin_amdgcn_global_load_lds(                                                 \
          (const __attribute__((address_space(1))) unsigned int*)(gptr[p] + (koff)),    \
          (__attribute__((address_space(3))) unsigned int*)(lptr[p] +                   \
                                                           (bufsel) * BUF_SHORTS),      \
          16, 0, 0);                                                                    \
    }                                                                                   \
  } while (0)

  // bitmask rows for this lane's 4 M-tiles: row(mt) = blk*128 + wr*64 + mt*16 + m
  const unsigned* ubp =
      ubits + (size_t)(blockIdx.x * 128 + wr * 64 + m) * GNW + (kbase >> 5);

  // per-lane B read bases (shorts): n = wc*32 + cc*16 + m, granule (st*4+q)^(m&7)
  const int bshift = (wc * 32 + m) * PHK;
  int swz8[NSTEP];
#pragma unroll
  for (int st = 0; st < NSTEP; ++st) swz8[st] = ((st * 4 + q) ^ (m & 7)) * 8;

  floatx4 acc[4][2];
#pragma unroll
  for (int mt = 0; mt < 4; ++mt)
#pragma unroll
    for (int cc = 0; cc < 2; ++cc) acc[mt][cc] = (floatx4){0.f, 0.f, 0.f, 0.f};

  STAGE(0, 0);  // preload phase 0

  int buf = 0;
  for (int ph = 0; ph < NPH; ++ph) {
    __syncthreads();  // staged buf complete (prev phase's stage drained here)
    // bits for THIS phase (L2/L3-resident; consumed after first ds_reads land)
    uintx4 cw[4];
#pragma unroll
    for (int mt = 0; mt < 4; ++mt)
      cw[mt] = *(const uintx4*)(ubp + (size_t)mt * (16 * GNW) + ph * 4);
    if (ph + 1 < NPH) STAGE(buf ^ 1, (ph + 1) * PHK);

    const unsigned short* bb = &bbuf[buf][0] + bshift;
#pragma unroll
    for (int st = 0; st < NSTEP; ++st) {
      short8 bf0 = *(const short8*)(bb + swz8[st]);
      short8 bf1 = *(const short8*)(bb + 16 * PHK + swz8[st]);
#pragma unroll
      for (int mt = 0; mt < 4; ++mt) {
        // A frag from bits: byte q of dword st of cw[mt]; identical to R1:
        // pk[j] halves = bits (q*8+2j, q*8+2j+1) -> 0x0000 / 0x3F80
        const unsigned b = (cw[mt][st] >> (q * 8)) & 0xFFu;
        const unsigned n0 = b & 0xFu, n1 = b >> 4;
        const unsigned w0 = n0 * 0x8001u, w1 = n1 * 0x8001u;
        intx4 pk;
        pk.x = (int)((w0 & 0x10001u) * 0x3F80u);
        pk.y = (int)(((w0 >> 2) & 0x10001u) * 0x3F80u);
        pk.z = (int)((w1 & 0x10001u) * 0x3F80u);
        pk.w = (int)(((w1 >> 2) & 0x10001u) * 0x3F80u);
        const short8 af = __builtin_bit_cast(short8, pk);
        acc[mt][0] = __builtin_amdgcn_mfma_f32_16x16x32_bf16(af, bf0, acc[mt][0], 0, 0, 0);
        acc[mt][1] = __builtin_amdgcn_mfma_f32_16x16x32_bf16(af, bf1, acc[mt][1], 0, 0, 0);
      }
    }
    buf ^= 1;
  }

  // Epilogue. C/D frag: col=lane&15 (=m), row=q*4+r.
  // Global: row = blk*128 + wr*64 + mt*16 + q*4 + r; col = wc*32 + cc*16 + m.
  float* pp = partials + (size_t)ks * OUT_ELEMS + (size_t)(blockIdx.x * 128) * GD;
#pragma unroll
  for (int mt = 0; mt < 4; ++mt)
#pragma unroll
    for (int cc = 0; cc < 2; ++cc)
#pragma unroll
      for (int r = 0; r < 4; ++r)
        pp[(size_t)(wr * 64 + mt * 16 + q * 4 + r) * GD + wc * 32 + cc * 16 + m] =
            acc[mt][cc][r];
}

// Kernel 3: out = x + sum of 4 partials (also un-poisons d_out)
__global__ __launch_bounds__(256) void reduce_kernel(const float* __restrict__ x,
                                                     const float* __restrict__ partials,
                                                     float* __restrict__ out) {
  size_t i = ((size_t)blockIdx.x * 256 + threadIdx.x) * 4;
  floatx4 v = *(const floatx4*)(x + i);
  v += *(const floatx4*)(partials + 0 * (size_t)OUT_ELEMS + i);
  v += *(const floatx4*)(partials + 1 * (size_t)OUT_ELEMS + i);
  v += *(const floatx4*)(partials + 2 * (size_t)OUT_ELEMS + i);
  v += *(const floatx4*)(partials + 3 * (size_t)OUT_ELEMS + i);
  *(floatx4*)(out + i) = v;
}

extern "C" void kernel_launch(void* const* d_in, const int* in_sizes, int n_in,
                              void* d_out, int out_size, void* d_ws, size_t ws_size,
                              hipStream_t stream) {
  const float* x = (const float*)d_in[0];
  const int* adj = (const int*)d_in[1];
  float* out = (float*)d_out;
  unsigned short* xT = (unsigned short*)d_ws;                          // 4 MiB
  float* partials = (float*)((char*)d_ws + (size_t)GN * GD * 2);       // 4 x 8 MiB
  unsigned* ubits = (unsigned*)((char*)d_ws + (size_t)GN * GD * 2 +
                                (size_t)KSPLIT * OUT_ELEMS * 4);       // 32 MiB @ 36 MiB

  prep_kernel<<<GN / 64, 256, 0, stream>>>(x, xT);
  pack_kernel<<<2048, 256, 0, stream>>>(adj, ubits);
  gemm_kernel<<<dim3(GN / 128, KSPLIT), 512, 0, stream>>>(ubits, xT, partials);
  reduce_kernel<<<OUT_ELEMS / 4 / 256, 256, 0, stream>>>(x, partials, out);
}